// Round 1
// baseline (961.133 us; speedup 1.0000x reference)
//
#include <hip/hip_runtime.h>
#include <hip/hip_bf16.h>

#define N_PAPER 30000
#define N_AUTHOR 20000
#define N_NODES 50000
#define N_EDGES 800000
#define D_PAPER 512
#define D_AUTHOR 256
#define N_HID 128
#define N_OUT 64
#define HEADS 2
#define NEG_SLOPE 0.2f

// ---------------- GEMM: out[M,NOUT] = act(A[M,K] @ W[K,NOUT] + bias) ----------------
// Tile: 32 rows x NOUT cols per block, 256 threads.
template<int NOUT, bool RELU>
__global__ __launch_bounds__(256) void gemm_kernel(
        const float* __restrict__ A, const float* __restrict__ W,
        const float* __restrict__ bias, float* __restrict__ out,
        int M, int K) {
    constexpr int CT  = (NOUT < 128) ? NOUT : 128;  // column threads
    constexpr int NG  = 256 / CT;                   // row groups
    constexpr int RPT = 32 / NG;                    // rows per thread
    constexpr int CPT = NOUT / CT;                  // cols per thread
    __shared__ __align__(16) float As[32][36];      // [k][row], padded

    const int tid = threadIdx.x;
    const int tx = tid % CT, ty = tid / CT;
    const int row0 = blockIdx.x * 32;

    float acc[RPT][CPT];
#pragma unroll
    for (int r = 0; r < RPT; r++)
#pragma unroll
        for (int j = 0; j < CPT; j++) acc[r][j] = 0.f;

    const int lrow = tid / 8;        // 0..31
    const int lk   = (tid % 8) * 4;  // 0..28

    for (int k0 = 0; k0 < K; k0 += 32) {
        float4 v = make_float4(0.f, 0.f, 0.f, 0.f);
        const int grow = row0 + lrow;
        if (grow < M)
            v = *reinterpret_cast<const float4*>(&A[(size_t)grow * K + k0 + lk]);
        __syncthreads();
        As[lk + 0][lrow] = v.x;
        As[lk + 1][lrow] = v.y;
        As[lk + 2][lrow] = v.z;
        As[lk + 3][lrow] = v.w;
        __syncthreads();

        const float* Wp = W + (size_t)k0 * NOUT + tx;
#pragma unroll 4
        for (int kk = 0; kk < 32; kk++) {
            float w[CPT];
#pragma unroll
            for (int j = 0; j < CPT; j++) w[j] = Wp[kk * NOUT + j * CT];
#pragma unroll
            for (int rq = 0; rq < RPT / 4; rq++) {
                float4 a4 = *reinterpret_cast<const float4*>(&As[kk][ty * RPT + rq * 4]);
                float av[4] = {a4.x, a4.y, a4.z, a4.w};
#pragma unroll
                for (int i = 0; i < 4; i++)
#pragma unroll
                    for (int j = 0; j < CPT; j++)
                        acc[rq * 4 + i][j] += av[i] * w[j];
            }
        }
    }

#pragma unroll
    for (int r = 0; r < RPT; r++) {
        const int grow = row0 + ty * RPT + r;
        if (grow >= M) continue;
#pragma unroll
        for (int j = 0; j < CPT; j++) {
            const int col = tx + j * CT;
            float o = acc[r][j];
            if (bias) o += bias[col];
            if (RELU) o = fmaxf(o, 0.f);
            out[(size_t)grow * NOUT + col] = o;
        }
    }
}

// ---------------- alpha_s / alpha_d per node ----------------
template<int H, int C>
__global__ void alpha_kernel(const float* __restrict__ h,
                             const float* __restrict__ a_src,
                             const float* __restrict__ a_dst,
                             float* __restrict__ as_out, float* __restrict__ ad_out) {
    const int n = blockIdx.x;
    const int tid = threadIdx.x;
    const int hd = tid >> 6;
    const int lane = tid & 63;
    const float* hp = h + (size_t)n * H * C + hd * C;
    const float* ap = a_src + hd * C;
    const float* dp = a_dst + hd * C;
    float ss = 0.f, sd = 0.f;
    for (int c = lane; c < C; c += 64) {
        float v = hp[c];
        ss += v * ap[c];
        sd += v * dp[c];
    }
#pragma unroll
    for (int off = 32; off; off >>= 1) {
        ss += __shfl_down(ss, off);
        sd += __shfl_down(sd, off);
    }
    if (lane == 0) {
        as_out[n * H + hd] = ss;
        ad_out[n * H + hd] = sd;
    }
}

// ---------------- ordered-uint float max encoding ----------------
__device__ __forceinline__ unsigned enc_f(float f) {
    unsigned b = __float_as_uint(f);
    return (b & 0x80000000u) ? ~b : (b | 0x80000000u);
}
__device__ __forceinline__ float dec_f(unsigned u) {
    unsigned b = (u & 0x80000000u) ? (u & 0x7FFFFFFFu) : ~u;
    return __uint_as_float(b);
}
__device__ __forceinline__ float lrelu(float x) {
    return (x > 0.f) ? x : NEG_SLOPE * x;
}

// ---------------- CSR build ----------------
__global__ void deg_kernel(const int* __restrict__ dst, int* __restrict__ deg) {
    int e = blockIdx.x * blockDim.x + threadIdx.x;
    if (e < N_EDGES) atomicAdd(&deg[dst[e]], 1);
}

__global__ __launch_bounds__(1024) void scan_kernel(const int* __restrict__ deg,
                                                    int* __restrict__ rowoff) {
    __shared__ int tmp[1024];
    __shared__ int carry;
    const int tid = threadIdx.x;
    if (tid == 0) carry = 0;
    __syncthreads();
    for (int base = 0; base < N_NODES; base += 1024) {
        int i = base + tid;
        int v = (i < N_NODES) ? deg[i] : 0;
        tmp[tid] = v;
        __syncthreads();
        for (int off = 1; off < 1024; off <<= 1) {
            int t = (tid >= off) ? tmp[tid - off] : 0;
            __syncthreads();
            tmp[tid] += t;
            __syncthreads();
        }
        int excl = carry + tmp[tid] - v;
        if (i < N_NODES) rowoff[i] = excl;
        int total = tmp[1023];
        __syncthreads();
        if (tid == 0) carry += total;
        __syncthreads();
    }
    if (tid == 0) rowoff[N_NODES] = carry;
}

__global__ void scatter_kernel(const int* __restrict__ src, const int* __restrict__ dst,
                               int* __restrict__ cursor, int* __restrict__ csr_src) {
    int e = blockIdx.x * blockDim.x + threadIdx.x;
    if (e >= N_EDGES) return;
    int d = dst[e];
    int pos = atomicAdd(&cursor[d], 1);
    csr_src[pos] = src[e];
}

// ---------------- edge softmax passes ----------------
template<int H>
__global__ void edge_max_kernel(const int* __restrict__ src, const int* __restrict__ dst,
                                const float* __restrict__ as_, const float* __restrict__ ad_,
                                unsigned* __restrict__ m) {
    int e = blockIdx.x * blockDim.x + threadIdx.x;
    if (e >= N_EDGES) return;
    int s = src[e], d = dst[e];
#pragma unroll
    for (int h = 0; h < H; h++) {
        float x = lrelu(as_[s * H + h] + ad_[d * H + h]);
        atomicMax(&m[d * H + h], enc_f(x));
    }
}

template<int H>
__global__ void edge_sum_kernel(const int* __restrict__ src, const int* __restrict__ dst,
                                const float* __restrict__ as_, const float* __restrict__ ad_,
                                const unsigned* __restrict__ m, float* __restrict__ denom) {
    int e = blockIdx.x * blockDim.x + threadIdx.x;
    if (e >= N_EDGES) return;
    int s = src[e], d = dst[e];
#pragma unroll
    for (int h = 0; h < H; h++) {
        float x = lrelu(as_[s * H + h] + ad_[d * H + h]);
        float p = __expf(x - dec_f(m[d * H + h]));
        atomicAdd(&denom[d * H + h], p);
    }
}

// ---------------- CSR aggregation: out[n, :] = sum_e alpha * h[src] (+bias, optional elu)
template<int H, int C, bool ELU>
__global__ void aggregate_kernel(const int* __restrict__ rowoff, const int* __restrict__ csr_src,
                                 const float* __restrict__ as_, const float* __restrict__ ad_,
                                 const unsigned* __restrict__ m, const float* __restrict__ denom,
                                 const float* __restrict__ hfeat, const float* __restrict__ bias,
                                 float* __restrict__ out) {
    constexpr int T = H * C;  // threads per block
    const int n = blockIdx.x;
    const int tid = threadIdx.x;
    const int hd = tid / C;

    __shared__ int s_src[T];
    __shared__ float s_w[H][T];

    float adv[H], mv[H], idv[H];
#pragma unroll
    for (int h = 0; h < H; h++) {
        adv[h] = ad_[n * H + h];
        mv[h] = dec_f(m[n * H + h]);
        idv[h] = 1.f / (denom[n * H + h] + 1e-16f);
    }

    const int r0 = rowoff[n], r1 = rowoff[n + 1];
    float acc = 0.f;
    for (int base = r0; base < r1; base += T) {
        const int cnt = min(T, r1 - base);
        __syncthreads();
        if (tid < cnt) {
            int s = csr_src[base + tid];
            s_src[tid] = s;
#pragma unroll
            for (int h = 0; h < H; h++) {
                float x = lrelu(as_[s * H + h] + adv[h]);
                s_w[h][tid] = __expf(x - mv[h]) * idv[h];
            }
        }
        __syncthreads();
#pragma unroll 4
        for (int j = 0; j < cnt; j++) {
            acc += hfeat[(size_t)s_src[j] * T + tid] * s_w[hd][j];
        }
    }
    float o = acc + bias[tid];
    if (ELU) o = (o > 0.f) ? o : (__expf(o) - 1.f);
    out[(size_t)n * T + tid] = o;
}

// ---------------- launch ----------------
extern "C" void kernel_launch(void* const* d_in, const int* in_sizes, int n_in,
                              void* d_out, int out_size, void* d_ws, size_t ws_size,
                              hipStream_t stream) {
    const float* x_paper  = (const float*)d_in[0];
    const float* x_author = (const float*)d_in[1];
    const int*   edge_idx = (const int*)d_in[2];
    const float* W1p = (const float*)d_in[3];
    const float* b1p = (const float*)d_in[4];
    const float* W1a = (const float*)d_in[5];
    const float* b1a = (const float*)d_in[6];
    const float* Wg1 = (const float*)d_in[7];
    const float* asrc1 = (const float*)d_in[8];
    const float* adst1 = (const float*)d_in[9];
    const float* bg1 = (const float*)d_in[10];
    const float* Wg2 = (const float*)d_in[11];
    const float* asrc2 = (const float*)d_in[12];
    const float* adst2 = (const float*)d_in[13];
    const float* bg2 = (const float*)d_in[14];
    float* out = (float*)d_out;

    const int* src = edge_idx;
    const int* dst = edge_idx + N_EDGES;

    char* ws = (char*)d_ws;
    size_t off = 0;
    auto alloc = [&](size_t bytes) -> void* {
        void* p = ws + off;
        off += (bytes + 255) & ~(size_t)255;
        return p;
    };
    float*    x      = (float*)alloc((size_t)N_NODES * N_HID * 4);          // encoder out
    float*    h1     = (float*)alloc((size_t)N_NODES * 2 * N_HID * 4);      // gat1 transform (also h2)
    float*    x2     = (float*)alloc((size_t)N_NODES * 2 * N_HID * 4);      // gat1 out + elu
    float*    as1    = (float*)alloc((size_t)N_NODES * HEADS * 4);
    float*    ad1    = (float*)alloc((size_t)N_NODES * HEADS * 4);
    unsigned* m1     = (unsigned*)alloc((size_t)N_NODES * HEADS * 4);
    float*    den1   = (float*)alloc((size_t)N_NODES * HEADS * 4);
    float*    as2    = (float*)alloc((size_t)N_NODES * 4);
    float*    ad2    = (float*)alloc((size_t)N_NODES * 4);
    unsigned* m2     = (unsigned*)alloc((size_t)N_NODES * 4);
    float*    den2   = (float*)alloc((size_t)N_NODES * 4);
    int*      deg    = (int*)alloc((size_t)N_NODES * 4);
    int*      rowoff = (int*)alloc((size_t)(N_NODES + 1) * 4);
    int*      cursor = (int*)alloc((size_t)N_NODES * 4);
    int*      csrsrc = (int*)alloc((size_t)N_EDGES * 4);
    float*    h2     = h1;  // alias: h1 dead once layer-1 aggregation done

    const int EB = (N_EDGES + 255) / 256;

    // --- CSR build (shared by both layers) ---
    hipMemsetAsync(deg, 0, N_NODES * 4, stream);
    deg_kernel<<<EB, 256, 0, stream>>>(dst, deg);
    scan_kernel<<<1, 1024, 0, stream>>>(deg, rowoff);
    hipMemcpyAsync(cursor, rowoff, N_NODES * 4, hipMemcpyDeviceToDevice, stream);
    scatter_kernel<<<EB, 256, 0, stream>>>(src, dst, cursor, csrsrc);

    // --- encoders ---
    gemm_kernel<N_HID, true><<<(N_PAPER + 31) / 32, 256, 0, stream>>>(
        x_paper, W1p, b1p, x, N_PAPER, D_PAPER);
    gemm_kernel<N_HID, true><<<(N_AUTHOR + 31) / 32, 256, 0, stream>>>(
        x_author, W1a, b1a, x + (size_t)N_PAPER * N_HID, N_AUTHOR, D_AUTHOR);

    // --- GAT layer 1 ---
    gemm_kernel<2 * N_HID, false><<<(N_NODES + 31) / 32, 256, 0, stream>>>(
        x, Wg1, nullptr, h1, N_NODES, N_HID);
    alpha_kernel<HEADS, N_HID><<<N_NODES, HEADS * 64, 0, stream>>>(
        h1, asrc1, adst1, as1, ad1);
    hipMemsetAsync(m1, 0, N_NODES * HEADS * 4, stream);
    hipMemsetAsync(den1, 0, N_NODES * HEADS * 4, stream);
    edge_max_kernel<HEADS><<<EB, 256, 0, stream>>>(src, dst, as1, ad1, m1);
    edge_sum_kernel<HEADS><<<EB, 256, 0, stream>>>(src, dst, as1, ad1, m1, den1);
    aggregate_kernel<HEADS, N_HID, true><<<N_NODES, HEADS * N_HID, 0, stream>>>(
        rowoff, csrsrc, as1, ad1, m1, den1, h1, bg1, x2);

    // --- GAT layer 2 ---
    gemm_kernel<N_OUT, false><<<(N_NODES + 31) / 32, 256, 0, stream>>>(
        x2, Wg2, nullptr, h2, N_NODES, 2 * N_HID);
    alpha_kernel<1, N_OUT><<<N_NODES, 64, 0, stream>>>(
        h2, asrc2, adst2, as2, ad2);
    hipMemsetAsync(m2, 0, N_NODES * 4, stream);
    hipMemsetAsync(den2, 0, N_NODES * 4, stream);
    edge_max_kernel<1><<<EB, 256, 0, stream>>>(src, dst, as2, ad2, m2);
    edge_sum_kernel<1><<<EB, 256, 0, stream>>>(src, dst, as2, ad2, m2, den2);
    aggregate_kernel<1, N_OUT, false><<<N_NODES, N_OUT, 0, stream>>>(
        rowoff, csrsrc, as2, ad2, m2, den2, h2, bg2, out);
}

// Round 3
// 715.453 us; speedup vs baseline: 1.3434x; 1.3434x over previous
//
#include <hip/hip_runtime.h>
#include <hip/hip_bf16.h>

#define N_PAPER 30000
#define N_AUTHOR 20000
#define N_NODES 50000
#define N_EDGES 800000
#define D_PAPER 512
#define D_AUTHOR 256
#define N_HID 128
#define N_OUT 64
#define HEADS 2
#define NEG_SLOPE 0.2f

typedef short s16x8 __attribute__((ext_vector_type(8)));
typedef float f32x4 __attribute__((ext_vector_type(4)));

__device__ __forceinline__ unsigned short f2b(float x) {
    unsigned u = __float_as_uint(x);
    u += 0x7fffu + ((u >> 16) & 1u);   // round-to-nearest-even
    return (unsigned short)(u >> 16);
}
__device__ __forceinline__ float b2f(unsigned short h) {
    return __uint_as_float(((unsigned)h) << 16);
}
__device__ __forceinline__ float lrelu(float x) {
    return (x > 0.f) ? x : NEG_SLOPE * x;
}

// ---------------- W pre-split+transpose: W[K][NOUT] fp32 -> WT_hi/WT_lo[NOUT][K] bf16 ----
__global__ void wsplit_kernel(const float* __restrict__ W, unsigned short* __restrict__ WTh,
                              unsigned short* __restrict__ WTl, int K, int NOUT) {
    int i = blockIdx.x * 256 + threadIdx.x;
    if (i >= K * NOUT) return;
    int k = i / NOUT, c = i % NOUT;
    float x = W[i];
    unsigned short h = f2b(x);
    float r = x - b2f(h);
    WTh[c * K + k] = h;
    WTl[c * K + k] = f2b(r);
}

// ---------------- split-bf16 MFMA GEMM: out[M,NOUT] = A[M,K] @ W ----------------
// Block: 256 threads = 4 waves; wave w owns rows [blk*64 + w*16, +16), all NOUT cols.
// OUTMODE: 0 = fp32 + bias + relu, 1 = bf16 plain, 2 = fp32 plain
template<int NOUT, int OUTMODE>
__global__ __launch_bounds__(256) void gemm_mfma_kernel(
        const float* __restrict__ A, const unsigned short* __restrict__ WTh,
        const unsigned short* __restrict__ WTl, const float* __restrict__ bias,
        float* __restrict__ outF, unsigned short* __restrict__ outB, int M, int K) {
    constexpr int NF = NOUT / 16;
    const int tid = threadIdx.x;
    const int wid = tid >> 6, lane = tid & 63;
    const int l16 = lane & 15, kg = lane >> 4;
    const int arow = blockIdx.x * 64 + wid * 16 + l16;
    const bool avalid = arow < M;
    const float* ap = A + (size_t)(avalid ? arow : 0) * K + kg * 8;
    const unsigned short* wph = WTh + (size_t)l16 * K + kg * 8;
    const unsigned short* wpl = WTl + (size_t)l16 * K + kg * 8;

    f32x4 acc[NF];
#pragma unroll
    for (int f = 0; f < NF; f++)
#pragma unroll
        for (int e = 0; e < 4; e++) acc[f][e] = 0.f;

    for (int k0 = 0; k0 < K; k0 += 32) {
        float4 u0 = make_float4(0.f, 0.f, 0.f, 0.f), u1 = u0;
        if (avalid) {
            u0 = *reinterpret_cast<const float4*>(ap + k0);
            u1 = *reinterpret_cast<const float4*>(ap + k0 + 4);
        }
        float av[8] = {u0.x, u0.y, u0.z, u0.w, u1.x, u1.y, u1.z, u1.w};
        s16x8 ah, al;
#pragma unroll
        for (int i = 0; i < 8; i++) {
            unsigned short h = f2b(av[i]);
            float r = av[i] - b2f(h);
            ah[i] = (short)h;
            al[i] = (short)f2b(r);
        }
#pragma unroll
        for (int f = 0; f < NF; f++) {
            const size_t wo = (size_t)f * 16 * K + k0;
            s16x8 bh = *reinterpret_cast<const s16x8*>(wph + wo);
            s16x8 bl = *reinterpret_cast<const s16x8*>(wpl + wo);
            acc[f] = __builtin_amdgcn_mfma_f32_16x16x32_bf16(al, bh, acc[f], 0, 0, 0);
            acc[f] = __builtin_amdgcn_mfma_f32_16x16x32_bf16(ah, bl, acc[f], 0, 0, 0);
            acc[f] = __builtin_amdgcn_mfma_f32_16x16x32_bf16(ah, bh, acc[f], 0, 0, 0);
        }
    }

    const int orow0 = blockIdx.x * 64 + wid * 16 + kg * 4;
#pragma unroll
    for (int f = 0; f < NF; f++) {
        const int col = f * 16 + l16;
        const float bv = (OUTMODE == 0) ? bias[col] : 0.f;
#pragma unroll
        for (int r = 0; r < 4; r++) {
            const int gr = orow0 + r;
            if (gr >= M) continue;
            float v = acc[f][r] + bv;
            if (OUTMODE == 0) {
                v = fmaxf(v, 0.f);
                outF[(size_t)gr * NOUT + col] = v;
            } else if (OUTMODE == 1) {
                outB[(size_t)gr * NOUT + col] = f2b(v);
            } else {
                outF[(size_t)gr * NOUT + col] = v;
            }
        }
    }
}

// ---------------- alpha dot products ----------------
__global__ __launch_bounds__(128) void alpha1_kernel(const unsigned short* __restrict__ h,
        const float* __restrict__ a_src, const float* __restrict__ a_dst,
        float* __restrict__ as_out, float* __restrict__ ad_out) {
    const int n = blockIdx.x;
    const int hd = threadIdx.x >> 6, lane = threadIdx.x & 63;
    const int c = lane * 2;
    const unsigned v = *reinterpret_cast<const unsigned*>(h + (size_t)n * 256 + hd * 128 + c);
    float x0 = b2f((unsigned short)(v & 0xffffu));
    float x1 = b2f((unsigned short)(v >> 16));
    const float* apv = a_src + hd * 128;
    const float* dpv = a_dst + hd * 128;
    float ss = x0 * apv[c] + x1 * apv[c + 1];
    float sd = x0 * dpv[c] + x1 * dpv[c + 1];
#pragma unroll
    for (int off = 32; off; off >>= 1) {
        ss += __shfl_down(ss, off);
        sd += __shfl_down(sd, off);
    }
    if (lane == 0) {
        as_out[n * 2 + hd] = ss;
        ad_out[n * 2 + hd] = sd;
    }
}

__global__ __launch_bounds__(64) void alpha2_kernel(const float* __restrict__ h,
        const float* __restrict__ a_src, const float* __restrict__ a_dst,
        float* __restrict__ as_out, float* __restrict__ ad_out) {
    const int n = blockIdx.x;
    const int lane = threadIdx.x;
    float v = h[(size_t)n * 64 + lane];
    float ss = v * a_src[lane];
    float sd = v * a_dst[lane];
#pragma unroll
    for (int off = 32; off; off >>= 1) {
        ss += __shfl_down(ss, off);
        sd += __shfl_down(sd, off);
    }
    if (lane == 0) {
        as_out[n] = ss;
        ad_out[n] = sd;
    }
}

// ---------------- CSR build ----------------
__global__ void deg_kernel(const int* __restrict__ dst, int* __restrict__ deg) {
    int e = blockIdx.x * blockDim.x + threadIdx.x;
    if (e < N_EDGES) atomicAdd(&deg[dst[e]], 1);
}

__global__ __launch_bounds__(1024) void scan_kernel(const int* __restrict__ deg,
                                                    int* __restrict__ rowoff) {
    __shared__ int tmp[1024];
    const int tid = threadIdx.x;
    constexpr int CH = (N_NODES + 1023) / 1024;
    const int t0 = tid * CH;
    int s = 0;
    for (int i = 0; i < CH; i++) {
        int idx = t0 + i;
        if (idx < N_NODES) s += deg[idx];
    }
    tmp[tid] = s;
    __syncthreads();
    for (int off = 1; off < 1024; off <<= 1) {
        int t = (tid >= off) ? tmp[tid - off] : 0;
        __syncthreads();
        tmp[tid] += t;
        __syncthreads();
    }
    int run = tmp[tid] - s;  // exclusive prefix
    for (int i = 0; i < CH; i++) {
        int idx = t0 + i;
        if (idx < N_NODES) {
            rowoff[idx] = run;
            run += deg[idx];
        }
    }
    if (tid == 1023) rowoff[N_NODES] = tmp[1023];
}

__global__ void scatter_kernel(const int* __restrict__ src, const int* __restrict__ dst,
                               int* __restrict__ cursor, int* __restrict__ csr_src) {
    int e = blockIdx.x * blockDim.x + threadIdx.x;
    if (e >= N_EDGES) return;
    int d = dst[e];
    int pos = atomicAdd(&cursor[d], 1);
    csr_src[pos] = src[e];
}

// ---------------- layer-1 aggregation: block per node, bf16 gather, fused softmax+ELU ----
__global__ __launch_bounds__(256) void agg1_kernel(
        const int* __restrict__ rowoff, const int* __restrict__ csr,
        const float* __restrict__ as_, const float* __restrict__ ad_,
        const unsigned short* __restrict__ hb, const float* __restrict__ bias,
        float* __restrict__ out) {
    const int n = blockIdx.x;
    const int tid = threadIdx.x;
    const int hd = tid >> 7;
    __shared__ int s_src[256];
    __shared__ float s_w[2][256];
    const float adv0 = ad_[n * 2], adv1 = ad_[n * 2 + 1];
    const int r0 = rowoff[n], r1 = rowoff[n + 1];
    float acc = 0.f, wsum = 0.f;
    for (int base = r0; base < r1; base += 256) {
        const int cnt = min(256, r1 - base);
        __syncthreads();
        if (tid < cnt) {
            int s = csr[base + tid];
            s_src[tid] = s;
            s_w[0][tid] = __expf(lrelu(as_[s * 2 + 0] + adv0));
            s_w[1][tid] = __expf(lrelu(as_[s * 2 + 1] + adv1));
        }
        __syncthreads();
#pragma unroll 4
        for (int j = 0; j < cnt; j++) {
            float w = s_w[hd][j];
            acc += b2f(hb[(size_t)s_src[j] * 256 + tid]) * w;
            wsum += w;
        }
    }
    float o = acc / (wsum + 1e-16f) + bias[tid];
    o = (o > 0.f) ? o : (__expf(o) - 1.f);  // ELU
    out[(size_t)n * 256 + tid] = o;
}

// ---------------- layer-2 aggregation: wave per node, fp32 gather ----------------
__global__ __launch_bounds__(256) void agg2_kernel(
        const int* __restrict__ rowoff, const int* __restrict__ csr,
        const float* __restrict__ as_, const float* __restrict__ ad_,
        const float* __restrict__ h, const float* __restrict__ bias,
        float* __restrict__ out) {
    const int wid = threadIdx.x >> 6, lane = threadIdx.x & 63;
    const int n = blockIdx.x * 4 + wid;
    if (n >= N_NODES) return;
    const float adv = ad_[n];
    const int r0 = rowoff[n], r1 = rowoff[n + 1];
    float acc = 0.f, wsum = 0.f;
    for (int base = r0; base < r1; base += 64) {
        const int cnt = min(64, r1 - base);
        int s = 0;
        float w = 0.f;
        if (lane < cnt) {
            s = csr[base + lane];
            w = __expf(lrelu(as_[s] + adv));
        }
        for (int j = 0; j < cnt; j++) {
            float wb = __shfl(w, j);
            int sb = __shfl(s, j);
            acc += h[(size_t)sb * 64 + lane] * wb;
            wsum += wb;
        }
    }
    out[(size_t)n * 64 + lane] = acc / (wsum + 1e-16f) + bias[lane];
}

// ---------------- launch ----------------
extern "C" void kernel_launch(void* const* d_in, const int* in_sizes, int n_in,
                              void* d_out, int out_size, void* d_ws, size_t ws_size,
                              hipStream_t stream) {
    const float* x_paper  = (const float*)d_in[0];
    const float* x_author = (const float*)d_in[1];
    const int*   edge_idx = (const int*)d_in[2];
    const float* W1p = (const float*)d_in[3];
    const float* b1p = (const float*)d_in[4];
    const float* W1a = (const float*)d_in[5];
    const float* b1a = (const float*)d_in[6];
    const float* Wg1 = (const float*)d_in[7];
    const float* asrc1 = (const float*)d_in[8];
    const float* adst1 = (const float*)d_in[9];
    const float* bg1 = (const float*)d_in[10];
    const float* Wg2 = (const float*)d_in[11];
    const float* asrc2 = (const float*)d_in[12];
    const float* adst2 = (const float*)d_in[13];
    const float* bg2 = (const float*)d_in[14];
    float* out = (float*)d_out;

    const int* src = edge_idx;
    const int* dst = edge_idx + N_EDGES;

    char* ws = (char*)d_ws;
    size_t off = 0;
    auto alloc = [&](size_t bytes) -> void* {
        void* p = ws + off;
        off += (bytes + 255) & ~(size_t)255;
        return p;
    };
    float*          x     = (float*)alloc((size_t)N_NODES * N_HID * 4);
    float*          x2    = (float*)alloc((size_t)N_NODES * 2 * N_HID * 4);
    float*          h2    = (float*)alloc((size_t)N_NODES * N_OUT * 4);
    unsigned short* h1b   = (unsigned short*)alloc((size_t)N_NODES * 2 * N_HID * 2);
    unsigned short* wt1ph = (unsigned short*)alloc((size_t)D_PAPER * N_HID * 2);
    unsigned short* wt1pl = (unsigned short*)alloc((size_t)D_PAPER * N_HID * 2);
    unsigned short* wt1ah = (unsigned short*)alloc((size_t)D_AUTHOR * N_HID * 2);
    unsigned short* wt1al = (unsigned short*)alloc((size_t)D_AUTHOR * N_HID * 2);
    unsigned short* wtg1h = (unsigned short*)alloc((size_t)N_HID * 2 * N_HID * 2);
    unsigned short* wtg1l = (unsigned short*)alloc((size_t)N_HID * 2 * N_HID * 2);
    unsigned short* wtg2h = (unsigned short*)alloc((size_t)2 * N_HID * N_OUT * 2);
    unsigned short* wtg2l = (unsigned short*)alloc((size_t)2 * N_HID * N_OUT * 2);
    float*          as1   = (float*)alloc((size_t)N_NODES * HEADS * 4);
    float*          ad1   = (float*)alloc((size_t)N_NODES * HEADS * 4);
    float*          as2   = (float*)alloc((size_t)N_NODES * 4);
    float*          ad2   = (float*)alloc((size_t)N_NODES * 4);
    int*            deg    = (int*)alloc((size_t)N_NODES * 4);
    int*            rowoff = (int*)alloc((size_t)(N_NODES + 1) * 4);
    int*            cursor = (int*)alloc((size_t)N_NODES * 4);
    int*            csrsrc = (int*)alloc((size_t)N_EDGES * 4);

    const int EB = (N_EDGES + 255) / 256;

    // --- W pre-split/transpose ---
    wsplit_kernel<<<(D_PAPER * N_HID + 255) / 256, 256, 0, stream>>>(W1p, wt1ph, wt1pl, D_PAPER, N_HID);
    wsplit_kernel<<<(D_AUTHOR * N_HID + 255) / 256, 256, 0, stream>>>(W1a, wt1ah, wt1al, D_AUTHOR, N_HID);
    wsplit_kernel<<<(N_HID * 2 * N_HID + 255) / 256, 256, 0, stream>>>(Wg1, wtg1h, wtg1l, N_HID, 2 * N_HID);
    wsplit_kernel<<<(2 * N_HID * N_OUT + 255) / 256, 256, 0, stream>>>(Wg2, wtg2h, wtg2l, 2 * N_HID, N_OUT);

    // --- CSR build ---
    hipMemsetAsync(deg, 0, N_NODES * 4, stream);
    deg_kernel<<<EB, 256, 0, stream>>>(dst, deg);
    scan_kernel<<<1, 1024, 0, stream>>>(deg, rowoff);
    hipMemcpyAsync(cursor, rowoff, N_NODES * 4, hipMemcpyDeviceToDevice, stream);
    scatter_kernel<<<EB, 256, 0, stream>>>(src, dst, cursor, csrsrc);

    // --- encoders ---
    gemm_mfma_kernel<N_HID, 0><<<(N_PAPER + 63) / 64, 256, 0, stream>>>(
        x_paper, wt1ph, wt1pl, b1p, x, nullptr, N_PAPER, D_PAPER);
    gemm_mfma_kernel<N_HID, 0><<<(N_AUTHOR + 63) / 64, 256, 0, stream>>>(
        x_author, wt1ah, wt1al, b1a, x + (size_t)N_PAPER * N_HID, nullptr, N_AUTHOR, D_AUTHOR);

    // --- GAT layer 1 ---
    gemm_mfma_kernel<2 * N_HID, 1><<<(N_NODES + 63) / 64, 256, 0, stream>>>(
        x, wtg1h, wtg1l, nullptr, nullptr, h1b, N_NODES, N_HID);
    alpha1_kernel<<<N_NODES, 128, 0, stream>>>(h1b, asrc1, adst1, as1, ad1);
    agg1_kernel<<<N_NODES, 256, 0, stream>>>(rowoff, csrsrc, as1, ad1, h1b, bg1, x2);

    // --- GAT layer 2 ---
    gemm_mfma_kernel<N_OUT, 2><<<(N_NODES + 63) / 64, 256, 0, stream>>>(
        x2, wtg2h, wtg2l, nullptr, h2, nullptr, N_NODES, 2 * N_HID);
    alpha2_kernel<<<N_NODES, 64, 0, stream>>>(h2, asrc2, adst2, as2, ad2);
    agg2_kernel<<<(N_NODES + 3) / 4, 256, 0, stream>>>(rowoff, csrsrc, as2, ad2, h2, bg2, out);
}